// Round 7
// baseline (186.870 us; speedup 1.0000x reference)
//
#include <hip/hip_runtime.h>
#include <hip/hip_bf16.h>

// Problem constants
#define Bsz 16
#define Lsz 512
#define Dsz 768
#define Tsz 12
#define Asz 64
#define N1  1536   // Tsz*Asz*2
#define Msz 8192   // Bsz*Lsz

typedef __bf16 bf16;
typedef bf16 bf16x2 __attribute__((ext_vector_type(2)));
typedef bf16 bf16x4 __attribute__((ext_vector_type(4)));
typedef bf16 bf16x8 __attribute__((ext_vector_type(8)));
typedef float f32x4 __attribute__((ext_vector_type(4)));
typedef unsigned long long u64;

__device__ inline void load_lds16(const bf16* g, bf16* l) {
    __builtin_amdgcn_global_load_lds((const __attribute__((address_space(1))) void*)g,
                                     (__attribute__((address_space(3))) void*)l, 16, 0, 0);
}

template<int L>
__device__ __forceinline__ void wait_vm() {
    if constexpr (L == 0) asm volatile("s_waitcnt vmcnt(0)" ::: "memory");
    else if constexpr (L == 2) asm volatile("s_waitcnt vmcnt(2)" ::: "memory");
    else if constexpr (L == 3) asm volatile("s_waitcnt vmcnt(3)" ::: "memory");
    else if constexpr (L == 4) asm volatile("s_waitcnt vmcnt(4)" ::: "memory");
    else if constexpr (L == 5) asm volatile("s_waitcnt vmcnt(5)" ::: "memory");
}

// ---- fused prep: cvt_input | cvt_w (transpose + de-interleave q/k) |
//      rope tables | mask bitfields ----
__global__ __launch_bounds__(256) void prep_kernel(
    const float* __restrict__ in, const float* __restrict__ W,
    const int* __restrict__ mask,
    bf16* __restrict__ Abf, bf16* __restrict__ Wt,
    float* __restrict__ Tc, float* __restrict__ Ts, u64* __restrict__ Mbits) {
    int blk = blockIdx.x;
    if (blk < 6144) {                       // cvt_input: 8192*768/4 threads
        int i = blk * 256 + threadIdx.x;
        float4 v = ((const float4*)in)[i];
        bf16x4 o;
        o[0] = (bf16)v.x; o[1] = (bf16)v.y; o[2] = (bf16)v.z; o[3] = (bf16)v.w;
        ((bf16x4*)Abf)[i] = o;
    } else if (blk < 6720) {                // cvt_w: N1*(Dsz/8) threads
        int tid = (blk - 6144) * 256 + threadIdx.x;
        int n  = tid % N1;                  // original output col
        int k0 = (tid / N1) * 8;
        bf16x8 o;
#pragma unroll
        for (int j = 0; j < 8; ++j) o[j] = (bf16)W[(size_t)(k0 + j) * N1 + n];
        // de-interleave: head th, col c -> row th*128 + (c&1)*64 + (c>>1)
        int th = n >> 7, c = n & 127;
        int nr = th * 128 + (c & 1) * 64 + (c >> 1);
        *(bf16x8*)(Wt + (size_t)nr * Dsz + k0) = o;
    } else if (blk < 6848) {                // rope tables: 512*64 threads
        int tid = (blk - 6720) * 256 + threadIdx.x;
        int l = tid >> 6, a = tid & 63;
        float theta = expf(-0.28782313662425575f * (float)(a >> 1));  // 10000^(-(a>>1)/32)
        float pe = (float)l * theta;
        float s, c;
        sincosf(pe, &s, &c);
        Tc[tid] = c; Ts[tid] = s;
    } else {                                // mask bits: 16*512 threads
        int tid = (blk - 6848) * 256 + threadIdx.x;
        u64 bal = __ballot(mask[tid] > 0);
        if ((tid & 63) == 0) Mbits[tid >> 6] = bal;
    }
}

__device__ __forceinline__ void rope_row(bf16* P, const float* tc, const float* ts) {
    float v[64];
#pragma unroll
    for (int c8 = 0; c8 < 8; ++c8) {
        bf16x8 x = *(const bf16x8*)(P + c8 * 8);
#pragma unroll
        for (int j = 0; j < 8; ++j) v[c8 * 8 + j] = (float)x[j];
    }
#pragma unroll
    for (int c8 = 0; c8 < 8; ++c8) {
        bf16x8 o;
#pragma unroll
        for (int j = 0; j < 8; ++j) {
            const int a  = c8 * 8 + j;
            const int a2 = (a < 32) ? (2 * a + 1) : (2 * (a - 32));
            const float sg = (a < 32) ? -1.f : 1.f;
            o[j] = (bf16)(v[a] * tc[a] + sg * v[a2] * ts[a]);
        }
        *(bf16x8*)(P + c8 * 8) = o;
    }
}

// ---- per-(z, quarter V) body: project Q[128] rows + K[512-128V] rows,
//      rope, then i-tiles {2V,2V+1} x all j-tiles of QK^T + mask ----
template<int V>
__device__ __forceinline__ void run_v(
    const bf16* __restrict__ Ab, const bf16* __restrict__ Wb,
    const float* __restrict__ bh,
    const float* __restrict__ Tc, const float* __restrict__ Ts,
    const u64* __restrict__ mb, float* __restrict__ ob, char* smem) {

    constexpr int gK0 = V * 128;           // first K (and Q) row
    constexpr int nK  = 512 - gK0;         // K rows this block projects
    constexpr int mK  = nK / 128;          // K m-frags per wave (4..1)
    constexpr int WKR = nK / 8;            // K rows per wave
    constexpr int ABUF = nK * 64;          // staged A bytes per buffer
    constexpr int PB   = ABUF + 8192;      // + W slice
    constexpr int L    = mK + 1;           // loads/thread/stage

    const int tid = threadIdx.x;
    const int wave = tid >> 6, lane = tid & 63;
    const int l15 = lane & 15, hi = lane >> 4;

    bf16* Kp = (bf16*)smem;                      // [nK][72]
    bf16* Qp = (bf16*)(smem + nK * 144);         // [128][72]

    f32x4 accK[mK][4] = {};
    f32x4 accQ[4] = {};

    auto stage = [&](int buf, int kk) {
        bf16* As = (bf16*)(smem + buf * PB);
        bf16* Ws = (bf16*)(smem + buf * PB + ABUF);
#pragma unroll
        for (int i = 0; i < mK; ++i) {
            int idx = i * 512 + tid;
            int r = idx >> 2, ch = (idx & 3) * 8;
            load_lds16(Ab + (size_t)(gK0 + r) * Dsz + kk + ch, As + r * 32 + ch);
        }
        load_lds16(Wb + (size_t)(tid >> 2) * Dsz + kk + (tid & 3) * 8,
                   Ws + (tid >> 2) * 32 + (tid & 3) * 8);
    };

    // ---------- phase 1: projection (triple-buffer, counted vmcnt) ----------
    stage(0, 0);
    stage(1, 32);
    wait_vm<L>();
    __builtin_amdgcn_s_barrier();

    int cur = 0;
    for (int t = 0; t < 24; ++t) {
        int stg = cur + 2; if (stg >= 3) stg -= 3;
        if (t + 2 < 24) stage(stg, (t + 2) * 32);

        const char* As = smem + cur * PB;
        const char* Ws = smem + cur * PB + ABUF;
        bf16x8 af[mK], aq, wq[4], wk[4];
#pragma unroll
        for (int m = 0; m < mK; ++m)
            af[m] = *(const bf16x8*)(As + (wave * WKR + m * 16 + l15) * 64 + hi * 16);
        aq = *(const bf16x8*)(As + (wave * 16 + l15) * 64 + hi * 16);
#pragma unroll
        for (int n = 0; n < 4; ++n) {
            wq[n] = *(const bf16x8*)(Ws + (n * 16 + l15) * 64 + hi * 16);
            wk[n] = *(const bf16x8*)(Ws + (64 + n * 16 + l15) * 64 + hi * 16);
        }
#pragma unroll
        for (int m = 0; m < mK; ++m)
#pragma unroll
            for (int n = 0; n < 4; ++n)
                accK[m][n] = __builtin_amdgcn_mfma_f32_16x16x32_bf16(af[m], wk[n], accK[m][n], 0, 0, 0);
#pragma unroll
        for (int n = 0; n < 4; ++n)
            accQ[n] = __builtin_amdgcn_mfma_f32_16x16x32_bf16(aq, wq[n], accQ[n], 0, 0, 0);

        if (t + 1 < 24) {
            if (t + 2 < 24) wait_vm<L>(); else wait_vm<0>();
            __builtin_amdgcn_s_barrier();
        }
        cur = cur + 1; if (cur >= 3) cur -= 3;
    }
    __syncthreads();     // staging dead; smem becomes Kp/Qp planes

    // ---------- phase 2: acc (+bias) -> planes ----------
    // C/D: col = n*16+l15 (= output a), row = hi*4+r
#pragma unroll
    for (int n = 0; n < 4; ++n) {
        const int a = n * 16 + l15;
        const float bq = bh[2 * a], bk = bh[2 * a + 1];
#pragma unroll
        for (int m = 0; m < mK; ++m) {
            const int rl = wave * WKR + m * 16 + hi * 4;
#pragma unroll
            for (int r = 0; r < 4; ++r)
                Kp[(rl + r) * 72 + a] = (bf16)(accK[m][n][r] + bk);
        }
        const int q0 = wave * 16 + hi * 4;
#pragma unroll
        for (int r = 0; r < 4; ++r)
            Qp[(q0 + r) * 72 + a] = (bf16)(accQ[n][r] + bq);
    }
    __syncthreads();

    // ---------- phase 3: rope ----------
    if (tid < nK)  rope_row(Kp + tid * 72, Tc + (size_t)(gK0 + tid) * 64, Ts + (size_t)(gK0 + tid) * 64);
    if (tid < 128) rope_row(Qp + tid * 72, Tc + (size_t)(gK0 + tid) * 64, Ts + (size_t)(gK0 + tid) * 64);
    __syncthreads();

    // ---------- phase 4: QK^T + mask; wave = j-tile, K frags reused ----------
    const int jt = wave;
    const int j0 = jt * 64;
    const u64 jb = mb[jt];
    bf16x8 k0[4], k1[4];
    if (jt >= 2 * V) {
#pragma unroll
        for (int ct = 0; ct < 4; ++ct) {
            const int kr = j0 - gK0 + ct * 16 + l15;
            k0[ct] = *(const bf16x8*)(Kp + kr * 72 + hi * 8);
            k1[ct] = *(const bf16x8*)(Kp + kr * 72 + 32 + hi * 8);
        }
    }
#pragma unroll
    for (int s = 0; s < 2; ++s) {
        const int it = 2 * V + s;
        const int i0 = it * 64;
        if (jt >= it) {
            const u64 ib = mb[it];
#pragma unroll
            for (int is = 0; is < 4; ++is) {
                const int ir = i0 + is * 16 + l15;           // global i
                const int ql = s * 64 + is * 16 + l15;       // Qp local row
                bf16x8 q0 = *(const bf16x8*)(Qp + ql * 72 + hi * 8);
                bf16x8 q1 = *(const bf16x8*)(Qp + ql * 72 + 32 + hi * 8);
                f32x4 a4[4] = {};
#pragma unroll
                for (int ct = 0; ct < 4; ++ct) {
                    a4[ct] = __builtin_amdgcn_mfma_f32_16x16x32_bf16(k0[ct], q0, a4[ct], 0, 0, 0);
                    a4[ct] = __builtin_amdgcn_mfma_f32_16x16x32_bf16(k1[ct], q1, a4[ct], 0, 0, 0);
                }
                const bool mi = (ib >> (is * 16 + l15)) & 1;
#pragma unroll
                for (int ct = 0; ct < 4; ++ct) {
                    const int jbase = ct * 16 + hi * 4;
                    f32x4 vv;
#pragma unroll
                    for (int r = 0; r < 4; ++r) {
                        const int j = j0 + jbase + r;
                        const bool keep = mi && ((jb >> (jbase + r)) & 1) && (ir <= j);
                        vv[r] = keep ? a4[ct][r] : -1e12f;
                    }
                    __builtin_nontemporal_store(vv, (f32x4*)(ob + (size_t)ir * Lsz + j0 + jbase));
                }
            }
        } else {
            f32x4 f = {-1e12f, -1e12f, -1e12f, -1e12f};
#pragma unroll
            for (int is = 0; is < 4; ++is) {
                const int ir = i0 + is * 16 + l15;
#pragma unroll
                for (int cc = 0; cc < 4; ++cc)
                    __builtin_nontemporal_store(f, (f32x4*)(ob + (size_t)ir * Lsz + j0 + hi * 16 + cc * 4));
            }
        }
    }
}

// 768 blocks = 4 quarters x 192 z; heavy quarters (V=0) dispatched first.
__global__ __launch_bounds__(512) void fused_kernel(
    const bf16* __restrict__ Abf, const bf16* __restrict__ Wt,
    const float* __restrict__ bias,
    const float* __restrict__ Tc, const float* __restrict__ Ts,
    const u64* __restrict__ Mbits, float* __restrict__ out) {
    __shared__ char smem[122880];          // max(3 stage bufs V=0, planes V=0)
    const int zo = blockIdx.x;             // 0..767
    const int v  = zo / 192;
    const int q  = zo % 192;
    const int z  = (q & 7) * 24 + (q >> 3);   // XCD-chunked (z and all its quarters share an XCD)
    const int b  = z / Tsz, th = z % Tsz;
    const bf16*  Ab = Abf + (size_t)b * Lsz * Dsz;
    const bf16*  Wb = Wt + (size_t)th * 128 * Dsz;
    const float* bh = bias + th * 128;
    const u64*   mb = Mbits + b * 8;
    float* ob = out + (size_t)z * Lsz * Lsz;
    switch (v) {
        case 0: run_v<0>(Ab, Wb, bh, Tc, Ts, mb, ob, smem); break;
        case 1: run_v<1>(Ab, Wb, bh, Tc, Ts, mb, ob, smem); break;
        case 2: run_v<2>(Ab, Wb, bh, Tc, Ts, mb, ob, smem); break;
        default: run_v<3>(Ab, Wb, bh, Tc, Ts, mb, ob, smem); break;
    }
}

extern "C" void kernel_launch(void* const* d_in, const int* in_sizes, int n_in,
                              void* d_out, int out_size, void* d_ws, size_t ws_size,
                              hipStream_t stream) {
    const float* in_f  = (const float*)d_in[0];
    const int*   amask = (const int*)d_in[1];
    const float* W     = (const float*)d_in[2];
    const float* bias  = (const float*)d_in[3];
    float* out = (float*)d_out;

    char* ws = (char*)d_ws;
    bf16*  Abf   = (bf16*)ws;                                // 12,582,912 B
    bf16*  Wt    = (bf16*)(ws + 12582912);                   //  2,359,296 B
    float* Tc    = (float*)(ws + 14942208);                  //    131,072 B
    float* Ts    = (float*)(ws + 15073280);                  //    131,072 B
    u64*   Mbits = (u64*)(ws + 15204352);                    //      1,024 B

    prep_kernel<<<6880, 256, 0, stream>>>(in_f, W, amask, Abf, Wt, Tc, Ts, Mbits);
    fused_kernel<<<768, 512, 0, stream>>>(Abf, Wt, bias, Tc, Ts, Mbits, out);
}

// Round 8
// 70.646 us; speedup vs baseline: 2.6451x; 2.6451x over previous
//
#include <hip/hip_runtime.h>
#include <hip/hip_bf16.h>

// Problem constants
#define Bsz 16
#define Lsz 512
#define Dsz 768
#define Tsz 12
#define Asz 64
#define N1  1536   // Tsz*Asz*2
#define Msz 8192   // Bsz*Lsz

typedef __bf16 bf16;
typedef bf16 bf16x2 __attribute__((ext_vector_type(2)));
typedef bf16 bf16x4 __attribute__((ext_vector_type(4)));
typedef bf16 bf16x8 __attribute__((ext_vector_type(8)));
typedef float f32x4 __attribute__((ext_vector_type(4)));
typedef unsigned long long u64;

__device__ inline void load_lds16(const bf16* g, bf16* l) {
    __builtin_amdgcn_global_load_lds((const __attribute__((address_space(1))) void*)g,
                                     (__attribute__((address_space(3))) void*)l, 16, 0, 0);
}

// ---- fused prep: cvt_input | cvt_w (straight transpose) | rope tables | mask bits ----
__global__ __launch_bounds__(256) void prep_kernel(
    const float* __restrict__ in, const float* __restrict__ W,
    const int* __restrict__ mask,
    bf16* __restrict__ Abf, bf16* __restrict__ Wt,
    float* __restrict__ Tc, float* __restrict__ Ts, u64* __restrict__ Mbits) {
    int blk = blockIdx.x;
    if (blk < 6144) {                       // cvt_input: 8192*768/4 threads
        int i = blk * 256 + threadIdx.x;
        float4 v = ((const float4*)in)[i];
        bf16x4 o;
        o[0] = (bf16)v.x; o[1] = (bf16)v.y; o[2] = (bf16)v.z; o[3] = (bf16)v.w;
        ((bf16x4*)Abf)[i] = o;
    } else if (blk < 6720) {                // cvt_w: N1*(Dsz/8) threads
        int tid = (blk - 6144) * 256 + threadIdx.x;
        int n  = tid % N1;
        int k0 = (tid / N1) * 8;
        bf16x8 o;
#pragma unroll
        for (int j = 0; j < 8; ++j) o[j] = (bf16)W[(size_t)(k0 + j) * N1 + n];
        *(bf16x8*)(Wt + (size_t)n * Dsz + k0) = o;
    } else if (blk < 6848) {                // rope tables: 512*64 threads
        int tid = (blk - 6720) * 256 + threadIdx.x;
        int l = tid >> 6, a = tid & 63;
        float theta = expf(-0.28782313662425575f * (float)(a >> 1));  // 10000^(-(a>>1)/32)
        float pe = (float)l * theta;
        float s, c;
        sincosf(pe, &s, &c);
        Tc[tid] = c; Ts[tid] = s;
    } else {                                // mask bits: 16*512 threads
        int tid = (blk - 6848) * 256 + threadIdx.x;
        u64 bal = __ballot(mask[tid] > 0);
        if ((tid & 63) == 0) Mbits[tid >> 6] = bal;
    }
}

__device__ __forceinline__ void rope_row(bf16* P, const float* tc, const float* ts) {
    float v[64];
#pragma unroll
    for (int c8 = 0; c8 < 8; ++c8) {
        bf16x8 x = *(const bf16x8*)(P + c8 * 8);
#pragma unroll
        for (int j = 0; j < 8; ++j) v[c8 * 8 + j] = (float)x[j];
    }
#pragma unroll
    for (int c8 = 0; c8 < 8; ++c8) {
        bf16x8 o;
#pragma unroll
        for (int j = 0; j < 8; ++j) {
            const int a  = c8 * 8 + j;
            const int a2 = (a < 32) ? (2 * a + 1) : (2 * (a - 32));
            const float sg = (a < 32) ? -1.f : 1.f;
            o[j] = (bf16)(v[a] * tc[a] + sg * v[a2] * ts[a]);
        }
        *(bf16x8*)(P + c8 * 8) = o;
    }
}

// ---- role-split grid: blocks 0..191 = fused proj+rope+QK (upper tiles);
//      blocks 192..255 = fill workers (strictly-below-diagonal -1e12 tiles).
// Fused: 512 thr (8 waves). LDS: staging 3x40960 aliased under Xq/Xk planes.
// Staging XOR-swizzle: LDS slot c of row r holds global chunk c^((r>>1)&3)
// (pre-swizzled global source, linear LDS dest); frag reads use hi^((l15>>1)&3).
#define PBUF 40960   // A 32768 + W 8192 per staging buffer
__global__ __launch_bounds__(512) void fused_kernel(
    const bf16* __restrict__ Abf, const bf16* __restrict__ Wt,
    const float* __restrict__ bias,
    const float* __restrict__ Tc, const float* __restrict__ Ts,
    const u64* __restrict__ Mbits, float* __restrict__ out) {
    __shared__ char smem[147456];
    const int bid = blockIdx.x;
    const int tid = threadIdx.x;

    if (bid >= 192) {
        // ---------------- fill role: 64 blocks, 3 z each ----------------
        const int w = bid - 192;
        const f32x4 f = {-1e12f, -1e12f, -1e12f, -1e12f};
        for (int zz = 0; zz < 3; ++zz) {
            float* ob = out + (size_t)(w * 3 + zz) * Lsz * Lsz;
#pragma unroll
            for (int it = 1; it < 8; ++it) {
                const int nch = it * 16;            // f32x4 chunks per row
                const int total = 64 * nch;
                for (int idx = tid; idx < total; idx += 512) {
                    const int r = idx / nch, c = idx - r * nch;
                    *((f32x4*)(ob + (size_t)(it * 64 + r) * Lsz) + c) = f;
                }
            }
        }
        return;
    }

    // ---------------- fused role ----------------
    bf16* Xq = (bf16*)smem;                  // [512][72]
    bf16* Xk = (bf16*)(smem + 73728);        // [512][72]

    const int z  = (bid & 7) * 24 + (bid >> 3);   // XCD-chunked
    const int b  = z / Tsz, th = z % Tsz;

    const int wave = tid >> 6, lane = tid & 63;
    const int l15 = lane & 15, hi = lane >> 4;
    const int wm = wave >> 1, wn = wave & 1;

    const bf16* Ab = Abf + (size_t)b * Lsz * Dsz;
    const bf16* Wb = Wt + (size_t)th * 128 * Dsz;
    const int lq = lane >> 2;
    const int schunk = ((lane & 3) ^ ((lane >> 3) & 3)) * 8;   // swizzled src chunk
    const int dchunk = (lane & 3) * 8;                          // linear dest chunk
    const int koff = (hi ^ ((l15 >> 1) & 3)) * 16;              // swizzled frag read

    // ---------- phase 1: projection 512x128 = A @ W_head^T ----------
    f32x4 acc[8][4] = {};

#define PSTAGE(buf, kk)                                                         \
    do {                                                                        \
        bf16* As = (bf16*)(smem + (buf) * PBUF);                                \
        bf16* Ws = (bf16*)(smem + (buf) * PBUF + 32768);                        \
        _Pragma("unroll")                                                       \
        for (int i = 0; i < 4; ++i) {                                           \
            int ra = wave * 64 + i * 16 + lq;                                   \
            load_lds16(Ab + (size_t)ra * Dsz + (kk) + schunk, As + ra * 32 + dchunk); \
        }                                                                       \
        int rw = wave * 16 + lq;                                                \
        load_lds16(Wb + (size_t)rw * Dsz + (kk) + schunk, Ws + rw * 32 + dchunk); \
    } while (0)

    PSTAGE(0, 0);
    PSTAGE(1, 32);
    asm volatile("s_waitcnt vmcnt(5)" ::: "memory");
    __builtin_amdgcn_s_barrier();

    int cur = 0;
    for (int t = 0; t < 24; ++t) {
        int stg = cur + 2; if (stg >= 3) stg -= 3;
        if (t + 2 < 24) PSTAGE(stg, (t + 2) * 32);

        const char* As = smem + cur * PBUF;
        const char* Ws = smem + cur * PBUF + 32768;
        bf16x8 af[8], bw[4];
#pragma unroll
        for (int mf = 0; mf < 8; ++mf)
            af[mf] = *(const bf16x8*)(As + (wm * 128 + mf * 16 + l15) * 64 + koff);
#pragma unroll
        for (int nf = 0; nf < 4; ++nf)
            bw[nf] = *(const bf16x8*)(Ws + (wn * 64 + nf * 16 + l15) * 64 + koff);
#pragma unroll
        for (int mf = 0; mf < 8; ++mf)
#pragma unroll
            for (int nf = 0; nf < 4; ++nf)
                acc[mf][nf] = __builtin_amdgcn_mfma_f32_16x16x32_bf16(af[mf], bw[nf], acc[mf][nf], 0, 0, 0);

        if (t + 1 < 24) {
            if (t + 2 < 24) asm volatile("s_waitcnt vmcnt(5)" ::: "memory");
            else            asm volatile("s_waitcnt vmcnt(0)" ::: "memory");
            __builtin_amdgcn_s_barrier();
        }
        cur = cur + 1; if (cur >= 3) cur -= 3;
    }
#undef PSTAGE
    __syncthreads();    // staging dead; smem becomes Xq/Xk planes

    // ---------- phase 2: acc (+bias) -> q/k planes ----------
    // C/D: col=l15 (+16n+64wn), row=hi*4+r. col c: even->q, odd->k, a=c>>1.
    {
        const int r0 = hi * 4;
#pragma unroll
        for (int nf = 0; nf < 4; ++nf) {
            const int c = wn * 64 + nf * 16 + l15;
            const float bv = bias[th * 128 + c];
            bf16* P = (c & 1) ? Xk : Xq;
            const int a = c >> 1;
#pragma unroll
            for (int mf = 0; mf < 8; ++mf) {
                const int rw = wm * 128 + mf * 16 + r0;
#pragma unroll
                for (int r = 0; r < 4; ++r)
                    P[(rw + r) * 72 + a] = (bf16)(acc[mf][nf][r] + bv);
            }
        }
    }
    __syncthreads();

    // ---------- phase 3: rope in place (thread = row l) ----------
    {
        const int l = tid;
        rope_row(Xq + l * 72, Tc + l * 64, Ts + l * 64);
        rope_row(Xk + l * 72, Tc + l * 64, Ts + l * 64);
    }
    __syncthreads();

    // ---------- phase 4: QK^T + mask, upper tiles only (fill role covers rest) ----------
    float* ob = out + (size_t)z * Lsz * Lsz;
    const u64* mb = Mbits + b * 8;
#pragma unroll
    for (int s = 0; s < 8; ++s) {
        const int it = s, jt = (wave - s) & 7;    // (it+jt)%8==wave: 4-5 compute tiles/wave
        if (jt < it) continue;
        const int i0 = it * 64, j0 = jt * 64;
        const u64 jb = mb[jt], ib = mb[it];
        bf16x8 k0[4], k1[4];
#pragma unroll
        for (int ct = 0; ct < 4; ++ct) {
            const int jr = j0 + ct * 16 + l15;
            k0[ct] = *(const bf16x8*)(Xk + jr * 72 + hi * 8);
            k1[ct] = *(const bf16x8*)(Xk + jr * 72 + 32 + hi * 8);
        }
#pragma unroll
        for (int is = 0; is < 4; ++is) {
            const int ir = i0 + is * 16 + l15;
            bf16x8 q0 = *(const bf16x8*)(Xq + ir * 72 + hi * 8);
            bf16x8 q1 = *(const bf16x8*)(Xq + ir * 72 + 32 + hi * 8);
            f32x4 a4[4] = {};
#pragma unroll
            for (int ct = 0; ct < 4; ++ct) {
                a4[ct] = __builtin_amdgcn_mfma_f32_16x16x32_bf16(k0[ct], q0, a4[ct], 0, 0, 0);
                a4[ct] = __builtin_amdgcn_mfma_f32_16x16x32_bf16(k1[ct], q1, a4[ct], 0, 0, 0);
            }
            const bool mi = (ib >> (is * 16 + l15)) & 1;
#pragma unroll
            for (int ct = 0; ct < 4; ++ct) {
                const int jbase = ct * 16 + hi * 4;
                f32x4 vv;
#pragma unroll
                for (int r = 0; r < 4; ++r) {
                    const int j = j0 + jbase + r;
                    const bool keep = mi && ((jb >> (jbase + r)) & 1) && (ir <= j);
                    vv[r] = keep ? a4[ct][r] : -1e12f;
                }
                *(f32x4*)(ob + (size_t)ir * Lsz + j0 + jbase) = vv;
            }
        }
    }
}

extern "C" void kernel_launch(void* const* d_in, const int* in_sizes, int n_in,
                              void* d_out, int out_size, void* d_ws, size_t ws_size,
                              hipStream_t stream) {
    const float* in_f  = (const float*)d_in[0];
    const int*   amask = (const int*)d_in[1];
    const float* W     = (const float*)d_in[2];
    const float* bias  = (const float*)d_in[3];
    float* out = (float*)d_out;

    char* ws = (char*)d_ws;
    bf16*  Abf   = (bf16*)ws;                                // 12,582,912 B
    bf16*  Wt    = (bf16*)(ws + 12582912);                   //  2,359,296 B
    float* Tc    = (float*)(ws + 14942208);                  //    131,072 B
    float* Ts    = (float*)(ws + 15073280);                  //    131,072 B
    u64*   Mbits = (u64*)(ws + 15204352);                    //      1,024 B

    prep_kernel<<<6880, 256, 0, stream>>>(in_f, W, amask, Abf, Wt, Tc, Ts, Mbits);
    fused_kernel<<<256, 512, 0, stream>>>(Abf, Wt, bias, Tc, Ts, Mbits, out);
}